// Round 1
// baseline (276.703 us; speedup 1.0000x reference)
//
#include <hip/hip_runtime.h>
#include <math.h>

#define Bb 512
#define Nn 128
#define NFG 8
#define NFR 256
#define NG 4

#define NTHREADS 512
#define NWAVES (NTHREADS / 64)
#define FEATS (Bb * Nn * NFG)

// ---------------- pre-kernel: factor the NFR=256 contraction ----------------
// M[g][f][f2] = sum_r Wt[g,f,r] * Wp[g,f2,r]          (256 floats)
// u[g][f]     = sum_r Wt[g,f,r] * bp[g,r]             (32)
// v[g][f]     = sum_r Wp[g,f,r] * bt[g,r]             (32)
// c[g]        = sum_r bt[g,r]   * bp[g,r]             (4)
__global__ void precompute_kernel(const float* __restrict__ Wt,
                                  const float* __restrict__ bt,
                                  const float* __restrict__ Wp,
                                  const float* __restrict__ bp,
                                  float* __restrict__ ws) {
    int t = threadIdx.x;  // 256 threads
    {
        int g = t >> 6, idx = t & 63, f = idx >> 3, f2 = idx & 7;
        const float* wt = Wt + (g * NFG + f) * NFR;
        const float* wp = Wp + (g * NFG + f2) * NFR;
        float s = 0.f;
        for (int r = 0; r < NFR; ++r) s += wt[r] * wp[r];
        ws[t] = s;
    }
    if (t < NG * NFG) {
        int g = t >> 3, f = t & 7;
        const float* wt = Wt + (g * NFG + f) * NFR;
        const float* wp = Wp + (g * NFG + f) * NFR;
        const float* btg = bt + g * NFR;
        const float* bpg = bp + g * NFR;
        float su = 0.f, sv = 0.f;
        for (int r = 0; r < NFR; ++r) {
            su += wt[r] * bpg[r];
            sv += wp[r] * btg[r];
        }
        ws[256 + t] = su;
        ws[288 + t] = sv;
    }
    if (t < NG) {
        const float* btg = bt + t * NFR;
        const float* bpg = bp + t * NFR;
        float s = 0.f;
        for (int r = 0; r < NFR; ++r) s += btg[r] * bpg[r];
        ws[320 + t] = s;
    }
}

// ---------------- main kernel: one block per batch element ----------------
__global__ __launch_bounds__(NTHREADS) void gcn_kernel(
    const float* __restrict__ X, const float* __restrict__ boxes,
    const float* __restrict__ We, const float* __restrict__ be,
    const float* __restrict__ Wg, const int* __restrict__ gtype,
    const float* __restrict__ ws, float* __restrict__ out) {

    __shared__ float xs[Nn][NFG + 1];        // relu(X We + be), padded (stride 9)
    __shared__ float as[NG][Nn][NFG + 1];    // a[g][n] = M_g^T x_n
    __shared__ float un[NG][Nn];             // u_g . x_n
    __shared__ float wn[NG][Nn];             // v_g . x_m + c_g
    __shared__ float px[Nn], py[Nn], rr[Nn];
    __shared__ float Ms[NG][NFG][NFG];
    __shared__ float Wgs[NG][NFG * NFG];
    __shared__ float us[NG][NFG], vs[NG][NFG], cs[NG];

    const int b = blockIdx.x;
    const int tid = threadIdx.x;

    // ---- stage constants ----
    if (tid < 256) {
        ((float*)Ms)[tid] = ws[tid];
    } else {  // tid in [256, 512)
        ((float*)Wgs)[tid - 256] = Wg[tid - 256];
    }
    if (tid < NG * NFG) {
        ((float*)us)[tid] = ws[256 + tid];
        ((float*)vs)[tid] = ws[288 + tid];
    }
    if (tid < NG) cs[tid] = ws[320 + tid];

    // ---- stage positions + fc_extend+relu ----
    if (tid < Nn) {
        const int n = tid;
        const float* bx = boxes + (size_t)(b * Nn + n) * 4;
        float x = bx[0], y = bx[1];
        px[n] = x;
        py[n] = y;
        rr[n] = x * x + y * y;
        const float* xr = X + (size_t)(b * Nn + n) * NFG;
        float xv[NFG];
#pragma unroll
        for (int f = 0; f < NFG; ++f) xv[f] = xr[f];
#pragma unroll
        for (int o = 0; o < NFG; ++o) {
            float s = be[o];
#pragma unroll
            for (int f = 0; f < NFG; ++f) s += xv[f] * We[f * NFG + o];
            xs[n][o] = fmaxf(s, 0.f);
        }
    }
    __syncthreads();

    // ---- per-head row precompute: a[g][n], un, wn (one (g,n) per thread) ----
    {
        const int g = tid >> 7, n = tid & 127;
        float xv[NFG];
#pragma unroll
        for (int f = 0; f < NFG; ++f) xv[f] = xs[n][f];
#pragma unroll
        for (int o = 0; o < NFG; ++o) {
            float s = 0.f;
#pragma unroll
            for (int f = 0; f < NFG; ++f) s += xv[f] * Ms[g][f][o];
            as[g][n][o] = s;
        }
        float su = 0.f, sv = 0.f;
#pragma unroll
        for (int f = 0; f < NFG; ++f) {
            su += us[g][f] * xv[f];
            sv += vs[g][f] * xv[f];
        }
        un[g][n] = su;
        wn[g][n] = sv + cs[g];
    }
    __syncthreads();

    // ---- main loop: wave per row; lane handles m=lane and m=lane+64 ----
    const int wave = tid >> 6, lane = tid & 63;
    const float thr2 = (gtype[0] == 0) ? 100.0f : 16.0f;
    const int m0 = lane, m1 = lane + 64;

    // lane-resident (row-invariant) m-side values
    float xm0[NFG], xm1[NFG];
#pragma unroll
    for (int f = 0; f < NFG; ++f) {
        xm0[f] = xs[m0][f];
        xm1[f] = xs[m1][f];
    }
    const float pxm0 = px[m0], pym0 = py[m0], rrm0 = rr[m0];
    const float pxm1 = px[m1], pym1 = py[m1], rrm1 = rr[m1];
    float wnm0[NG], wnm1[NG];
#pragma unroll
    for (int g = 0; g < NG; ++g) {
        wnm0[g] = wn[g][m0];
        wnm1[g] = wn[g][m1];
    }
    const int o = lane & 7;
    float wgcol[NG][NFG];  // Wg[g][f][o] column for this lane's o
#pragma unroll
    for (int g = 0; g < NG; ++g)
#pragma unroll
        for (int f = 0; f < NFG; ++f) wgcol[g][f] = Wgs[g][f * NFG + o];

    const float NEG_INF = -__builtin_inff();

    for (int n = wave; n < Nn; n += NWAVES) {
        const float pnx = px[n], pny = py[n], rn = rr[n];
        // mask: dist > thr  <=>  d2 > thr^2  (NaN/negative-d2 -> false, as in ref)
        const float d20 = (rn - 2.f * (pnx * pxm0 + pny * pym0)) + rrm0;
        const float d21 = (rn - 2.f * (pnx * pxm1 + pny * pym1)) + rrm1;
        const bool mask0 = d20 > thr2;
        const bool mask1 = d21 > thr2;

        float acc_o = 0.f;

#pragma unroll
        for (int g = 0; g < NG; ++g) {
            float a[NFG];
#pragma unroll
            for (int f = 0; f < NFG; ++f) a[f] = as[g][n][f];  // broadcast
            const float ug = un[g][n];

            float s0 = ug + wnm0[g], s1 = ug + wnm1[g];
#pragma unroll
            for (int f = 0; f < NFG; ++f) {
                s0 += a[f] * xm0[f];
                s1 += a[f] * xm1[f];
            }
            s0 *= 0.0625f;
            s1 *= 0.0625f;
            if (mask0) s0 = NEG_INF;
            if (mask1) s1 = NEG_INF;

            float mx = fmaxf(s0, s1);
#pragma unroll
            for (int off = 32; off > 0; off >>= 1) mx = fmaxf(mx, __shfl_xor(mx, off));
            const float e0 = mask0 ? 0.f : __expf(s0 - mx);
            const float e1 = mask1 ? 0.f : __expf(s1 - mx);
            float ssum = e0 + e1;
#pragma unroll
            for (int off = 32; off > 0; off >>= 1) ssum += __shfl_xor(ssum, off);
            const float inv = 1.0f / ssum;
            const float p0 = e0 * inv, p1 = e1 * inv;

            if (g == NG - 1) {
                float* arow = out + FEATS + (size_t)(b * Nn + n) * Nn;
                arow[m0] = p0;
                arow[m1] = p1;
            }

            // agg[f] = sum_m p_m x[m][f]; butterfly-reduced so all lanes hold it
            float agg[NFG];
#pragma unroll
            for (int f = 0; f < NFG; ++f) {
                float v = p0 * xm0[f] + p1 * xm1[f];
#pragma unroll
                for (int off = 32; off > 0; off >>= 1) v += __shfl_xor(v, off);
                agg[f] = v;
            }
            // head_out[o] = relu(agg . Wg[g][:,o]) for this lane's o
            float t = 0.f;
#pragma unroll
            for (int f = 0; f < NFG; ++f) t += agg[f] * wgcol[g][f];
            acc_o += fmaxf(t, 0.f);
        }

        if (lane < NFG) out[(size_t)(b * Nn + n) * NFG + lane] = acc_o * 0.25f;
    }
}

extern "C" void kernel_launch(void* const* d_in, const int* in_sizes, int n_in,
                              void* d_out, int out_size, void* d_ws, size_t ws_size,
                              hipStream_t stream) {
    const float* X     = (const float*)d_in[0];
    const float* boxes = (const float*)d_in[1];
    const float* We    = (const float*)d_in[2];
    const float* be    = (const float*)d_in[3];
    const float* Wt    = (const float*)d_in[4];
    const float* bt    = (const float*)d_in[5];
    const float* Wp    = (const float*)d_in[6];
    const float* bp    = (const float*)d_in[7];
    const float* Wg    = (const float*)d_in[8];
    const int*   gt    = (const int*)d_in[9];
    float* out = (float*)d_out;
    float* ws  = (float*)d_ws;

    precompute_kernel<<<1, 256, 0, stream>>>(Wt, bt, Wp, bp, ws);
    gcn_kernel<<<Bb, NTHREADS, 0, stream>>>(X, boxes, We, be, Wg, gt, ws, out);
}

// Round 8
// 257.806 us; speedup vs baseline: 1.0733x; 1.0733x over previous
//
#include <hip/hip_runtime.h>
#include <hip/hip_bf16.h>

#define Bb 512
#define Nn 128
#define NFG 8
#define NFR 256
#define NG 4

#define NTHREADS 512
#define NWAVES (NTHREADS / 64)
#define FEATS (Bb * Nn * NFG)

// ---------------- pre-kernel: factor the NFR=256 contraction ----------------
// Wide version (324 blocks x 64 lanes): same ws layout as round 1.
// M[g][f][f2] = sum_r Wt[g,f,r] * Wp[g,f2,r]          ws[0..256)
// u[g][f]     = sum_r Wt[g,f,r] * bp[g,r]             ws[256..288)
// v[g][f]     = sum_r Wp[g,f,r] * bt[g,r]             ws[288..320)
// c[g]        = sum_r bt[g,r]   * bp[g,r]             ws[320..324)
// (M/u/v/c feed only the continuous sim path -> rounding differences vs the
//  round-1 serial precompute are ~1e-6, far below threshold. Mask untouched.)
__global__ __launch_bounds__(64) void precompute_kernel(
    const float* __restrict__ Wt, const float* __restrict__ bt,
    const float* __restrict__ Wp, const float* __restrict__ bp,
    float* __restrict__ ws) {
    const int bid = blockIdx.x;  // 0..323
    const int l = threadIdx.x;   // 64
    const float *p, *q;
    if (bid < 256) {
        int g = bid >> 6, f = (bid >> 3) & 7, f2 = bid & 7;
        p = Wt + (g * NFG + f) * NFR;
        q = Wp + (g * NFG + f2) * NFR;
    } else if (bid < 288) {
        int i = bid - 256, g = i >> 3, f = i & 7;
        p = Wt + (g * NFG + f) * NFR;
        q = bp + g * NFR;
    } else if (bid < 320) {
        int i = bid - 288, g = i >> 3, f = i & 7;
        p = Wp + (g * NFG + f) * NFR;
        q = bt + g * NFR;
    } else {
        int g = bid - 320;
        p = bt + g * NFR;
        q = bp + g * NFR;
    }
    float s = 0.f;
#pragma unroll
    for (int r = 0; r < NFR / 64; ++r) s = fmaf(p[l + 64 * r], q[l + 64 * r], s);
#pragma unroll
    for (int off = 32; off > 0; off >>= 1) s += __shfl_xor(s, off);
    if (l == 0) ws[bid] = s;
}

// ---------------- main kernel: one block per batch element ----------------
// VERBATIM round-1 source (known-passing binary; do not touch — the mask
// bits depend on this function's exact codegen).
__global__ __launch_bounds__(NTHREADS) void gcn_kernel(
    const float* __restrict__ X, const float* __restrict__ boxes,
    const float* __restrict__ We, const float* __restrict__ be,
    const float* __restrict__ Wg, const int* __restrict__ gtype,
    const float* __restrict__ ws, float* __restrict__ out) {

    __shared__ float xs[Nn][NFG + 1];        // relu(X We + be), padded (stride 9)
    __shared__ float as[NG][Nn][NFG + 1];    // a[g][n] = M_g^T x_n
    __shared__ float un[NG][Nn];             // u_g . x_n
    __shared__ float wn[NG][Nn];             // v_g . x_m + c_g
    __shared__ float px[Nn], py[Nn], rr[Nn];
    __shared__ float Ms[NG][NFG][NFG];
    __shared__ float Wgs[NG][NFG * NFG];
    __shared__ float us[NG][NFG], vs[NG][NFG], cs[NG];

    const int b = blockIdx.x;
    const int tid = threadIdx.x;

    // ---- stage constants ----
    if (tid < 256) {
        ((float*)Ms)[tid] = ws[tid];
    } else {  // tid in [256, 512)
        ((float*)Wgs)[tid - 256] = Wg[tid - 256];
    }
    if (tid < NG * NFG) {
        ((float*)us)[tid] = ws[256 + tid];
        ((float*)vs)[tid] = ws[288 + tid];
    }
    if (tid < NG) cs[tid] = ws[320 + tid];

    // ---- stage positions + fc_extend+relu ----
    if (tid < Nn) {
        const int n = tid;
        const float* bx = boxes + (size_t)(b * Nn + n) * 4;
        float x = bx[0], y = bx[1];
        px[n] = x;
        py[n] = y;
        rr[n] = x * x + y * y;
        const float* xr = X + (size_t)(b * Nn + n) * NFG;
        float xv[NFG];
#pragma unroll
        for (int f = 0; f < NFG; ++f) xv[f] = xr[f];
#pragma unroll
        for (int o = 0; o < NFG; ++o) {
            float s = be[o];
#pragma unroll
            for (int f = 0; f < NFG; ++f) s += xv[f] * We[f * NFG + o];
            xs[n][o] = fmaxf(s, 0.f);
        }
    }
    __syncthreads();

    // ---- per-head row precompute: a[g][n], un, wn (one (g,n) per thread) ----
    {
        const int g = tid >> 7, n = tid & 127;
        float xv[NFG];
#pragma unroll
        for (int f = 0; f < NFG; ++f) xv[f] = xs[n][f];
#pragma unroll
        for (int o = 0; o < NFG; ++o) {
            float s = 0.f;
#pragma unroll
            for (int f = 0; f < NFG; ++f) s += xv[f] * Ms[g][f][o];
            as[g][n][o] = s;
        }
        float su = 0.f, sv = 0.f;
#pragma unroll
        for (int f = 0; f < NFG; ++f) {
            su += us[g][f] * xv[f];
            sv += vs[g][f] * xv[f];
        }
        un[g][n] = su;
        wn[g][n] = sv + cs[g];
    }
    __syncthreads();

    // ---- main loop: wave per row; lane handles m=lane and m=lane+64 ----
    const int wave = tid >> 6, lane = tid & 63;
    const float thr2 = (gtype[0] == 0) ? 100.0f : 16.0f;
    const int m0 = lane, m1 = lane + 64;

    // lane-resident (row-invariant) m-side values
    float xm0[NFG], xm1[NFG];
#pragma unroll
    for (int f = 0; f < NFG; ++f) {
        xm0[f] = xs[m0][f];
        xm1[f] = xs[m1][f];
    }
    const float pxm0 = px[m0], pym0 = py[m0], rrm0 = rr[m0];
    const float pxm1 = px[m1], pym1 = py[m1], rrm1 = rr[m1];
    float wnm0[NG], wnm1[NG];
#pragma unroll
    for (int g = 0; g < NG; ++g) {
        wnm0[g] = wn[g][m0];
        wnm1[g] = wn[g][m1];
    }
    const int o = lane & 7;
    float wgcol[NG][NFG];  // Wg[g][f][o] column for this lane's o
#pragma unroll
    for (int g = 0; g < NG; ++g)
#pragma unroll
        for (int f = 0; f < NFG; ++f) wgcol[g][f] = Wgs[g][f * NFG + o];

    const float NEG_INF = -__builtin_inff();

    for (int n = wave; n < Nn; n += NWAVES) {
        const float pnx = px[n], pny = py[n], rn = rr[n];
        // mask: dist > thr  <=>  d2 > thr^2  (NaN/negative-d2 -> false, as in ref)
        const float d20 = (rn - 2.f * (pnx * pxm0 + pny * pym0)) + rrm0;
        const float d21 = (rn - 2.f * (pnx * pxm1 + pny * pym1)) + rrm1;
        const bool mask0 = d20 > thr2;
        const bool mask1 = d21 > thr2;

        float acc_o = 0.f;

#pragma unroll
        for (int g = 0; g < NG; ++g) {
            float a[NFG];
#pragma unroll
            for (int f = 0; f < NFG; ++f) a[f] = as[g][n][f];  // broadcast
            const float ug = un[g][n];

            float s0 = ug + wnm0[g], s1 = ug + wnm1[g];
#pragma unroll
            for (int f = 0; f < NFG; ++f) {
                s0 += a[f] * xm0[f];
                s1 += a[f] * xm1[f];
            }
            s0 *= 0.0625f;
            s1 *= 0.0625f;
            if (mask0) s0 = NEG_INF;
            if (mask1) s1 = NEG_INF;

            float mx = fmaxf(s0, s1);
#pragma unroll
            for (int off = 32; off > 0; off >>= 1) mx = fmaxf(mx, __shfl_xor(mx, off));
            const float e0 = mask0 ? 0.f : __expf(s0 - mx);
            const float e1 = mask1 ? 0.f : __expf(s1 - mx);
            float ssum = e0 + e1;
#pragma unroll
            for (int off = 32; off > 0; off >>= 1) ssum += __shfl_xor(ssum, off);
            const float inv = 1.0f / ssum;
            const float p0 = e0 * inv, p1 = e1 * inv;

            if (g == NG - 1) {
                float* arow = out + FEATS + (size_t)(b * Nn + n) * Nn;
                arow[m0] = p0;
                arow[m1] = p1;
            }

            // agg[f] = sum_m p_m x[m][f]; butterfly-reduced so all lanes hold it
            float agg[NFG];
#pragma unroll
            for (int f = 0; f < NFG; ++f) {
                float v = p0 * xm0[f] + p1 * xm1[f];
#pragma unroll
                for (int off = 32; off > 0; off >>= 1) v += __shfl_xor(v, off);
                agg[f] = v;
            }
            // head_out[o] = relu(agg . Wg[g][:,o]) for this lane's o
            float t = 0.f;
#pragma unroll
            for (int f = 0; f < NFG; ++f) t += agg[f] * wgcol[g][f];
            acc_o += fmaxf(t, 0.f);
        }

        if (lane < NFG) out[(size_t)(b * Nn + n) * NFG + lane] = acc_o * 0.25f;
    }
}

extern "C" void kernel_launch(void* const* d_in, const int* in_sizes, int n_in,
                              void* d_out, int out_size, void* d_ws, size_t ws_size,
                              hipStream_t stream) {
    const float* X     = (const float*)d_in[0];
    const float* boxes = (const float*)d_in[1];
    const float* We    = (const float*)d_in[2];
    const float* be    = (const float*)d_in[3];
    const float* Wt    = (const float*)d_in[4];
    const float* bt    = (const float*)d_in[5];
    const float* Wp    = (const float*)d_in[6];
    const float* bp    = (const float*)d_in[7];
    const float* Wg    = (const float*)d_in[8];
    const int*   gt    = (const int*)d_in[9];
    float* out = (float*)d_out;
    float* ws  = (float*)d_ws;

    precompute_kernel<<<324, 64, 0, stream>>>(Wt, bt, Wp, bp, ws);
    gcn_kernel<<<Bb, NTHREADS, 0, stream>>>(X, boxes, We, be, Wg, gt, ws, out);
}

// Round 14
// 118.569 us; speedup vs baseline: 2.3337x; 2.1743x over previous
//
#include <hip/hip_runtime.h>
#include <math.h>

#define Bb 512
#define Nn 128
#define NFG 8
#define NFR 256
#define NG 4
#define FEATS (Bb * Nn * NFG)

// softmax uses exp((raw - 32)/16) = exp2(raw*EXP_C - EXP_SH); shift cancels.
#define EXP_C 0.0901684417f    // log2(e)/16
#define EXP_SH 2.885390082f    // 2*log2(e)

// ws layout (floats): [0,256) M[g][f][o]; [256,288) u[g][f]; [288,320) v[g][f];
// [320,324) c[g]; [1024, 1024+65536) inv3[b][n]
#define WS_INV 1024

// ---- mask: inline-asm pinned to the modeled round-1 codegen ----
// r1 (PASS) source:  rr = x*x + y*y;  d2 = (rn - 2*(pnx*pxm + pny*pym)) + rrm
// LLVM contraction model (DAGCombine fuses FIRST fmul of fadd; fsub(x, fmul)
// -> fma(-a,b,x); *2 exact):
//   rr  = fma(x, x, RN(y*y))          (v_mul y,y ; v_fmac x,x)
//   e   = fma(pnx, pxm, RN(pny*pym))  (v_mul pny,pym ; v_fmac pnx,pxm)
//   d2  = RN( fma(e, -2, rn) + rrm )  (v_fma ; v_add)
//   mask = d2 > thr2
// asm is context-immune -> bitwise identical in kernelA and kernelB, and
// (if model correct) identical to the r1 binary's mask bits.
// Diagonal: e(n,n) == rr(n) bitwise (same sequence) -> d2 == 0 -> unmasked.
__device__ __forceinline__ float asm_rr(float x, float y) {
    float d;
    asm("v_mul_f32 %0, %2, %2\n\t"
        "v_fmac_f32 %0, %1, %1"
        : "=&v"(d) : "v"(x), "v"(y));
    return d;
}
__device__ __forceinline__ bool asm_mask(float pnx, float pny, float rn,
                                         float pxm, float pym, float rrm,
                                         float thr2) {
    float e, d;
    asm("v_mul_f32 %0, %2, %4\n\t"
        "v_fmac_f32 %0, %1, %3"
        : "=&v"(e) : "v"(pnx), "v"(pny), "v"(pxm), "v"(pym));
    asm("v_fma_f32 %0, %1, -2.0, %2\n\t"
        "v_add_f32 %0, %0, %3"
        : "=&v"(d) : "v"(e), "v"(rn), "v"(rrm));
    return d > thr2;
}

// ---------------- precompute: factor the NFR=256 contraction (324 blocks) ----
__global__ __launch_bounds__(64) void precompute_kernel(
    const float* __restrict__ Wt, const float* __restrict__ bt,
    const float* __restrict__ Wp, const float* __restrict__ bp,
    float* __restrict__ ws) {
    const int bid = blockIdx.x;  // 0..323
    const int l = threadIdx.x;   // 64
    const float *p, *q;
    if (bid < 256) {
        int g = bid >> 6, f = (bid >> 3) & 7, f2 = bid & 7;
        p = Wt + (g * NFG + f) * NFR;
        q = Wp + (g * NFG + f2) * NFR;
    } else if (bid < 288) {
        int i = bid - 256, g = i >> 3, f = i & 7;
        p = Wt + (g * NFG + f) * NFR;
        q = bp + g * NFR;
    } else if (bid < 320) {
        int i = bid - 288, g = i >> 3, f = i & 7;
        p = Wp + (g * NFG + f) * NFR;
        q = bt + g * NFR;
    } else {
        int g = bid - 320;
        p = bt + g * NFR;
        q = bp + g * NFR;
    }
    float s = 0.f;
#pragma unroll
    for (int r = 0; r < NFR / 64; ++r) s = fmaf(p[l + 64 * r], q[l + 64 * r], s);
#pragma unroll
    for (int off = 32; off > 0; off >>= 1) s += __shfl_xor(s, off);
    if (l == 0) ws[bid] = s;
}

// ---------------- kernel A: feats + softmax denominators ----------------
// block = 512 threads: thread -> (n = tid>>2, c = tid&3); all 4 heads,
// m in {4i+c}. grid = 512 (one block per b).
__global__ __launch_bounds__(512) void kernelA(
    const float* __restrict__ X, const float* __restrict__ boxes,
    const float* __restrict__ We, const float* __restrict__ be,
    const float* __restrict__ Wg, const int* __restrict__ gtype,
    const float* __restrict__ ws, float* __restrict__ out,
    float* __restrict__ invws) {

    __shared__ float4 xs4[Nn * 2];        // relu(X We + be) rows [128][8]
    __shared__ float4 pos4[Nn];           // x, y, rr(asm), 0
    __shared__ float4 wn4[Nn];            // w_g(m) = v_g.x_m + c_g, 4 heads
    __shared__ float4 un4[Nn];            // u_g(n) = u_g.x_n, 4 heads
    __shared__ float4 as4[Nn * NG * 2];   // a[n][g][8]
    __shared__ float Msh[256], Wgsh[256];
    __shared__ float ush[32], vsh[32], csh[4];
    __shared__ float Weh[64], beh[8];

    const int b = blockIdx.x;
    const int tid = threadIdx.x;

    // ---- stage constants ----
    if (tid < 256) Msh[tid] = ws[tid];
    else Wgsh[tid - 256] = Wg[tid - 256];
    if (tid >= 256 && tid < 288) ush[tid - 256] = ws[tid];
    if (tid >= 288 && tid < 320) vsh[tid - 288] = ws[tid];
    if (tid >= 320 && tid < 324) csh[tid - 320] = ws[tid];
    if (tid < 64) Weh[tid] = We[tid];
    if (tid < 8) beh[tid] = be[tid];
    __syncthreads();

    // ---- rows: pos + x = relu(X We + be) ----
    if (tid < Nn) {
        const int r = tid;
        const float4 bx = *(const float4*)(boxes + ((size_t)b * Nn + r) * 4);
        pos4[r] = make_float4(bx.x, bx.y, asm_rr(bx.x, bx.y), 0.f);
        const float4 xlo = *(const float4*)(X + ((size_t)b * Nn + r) * NFG);
        const float4 xhi = *(const float4*)(X + ((size_t)b * Nn + r) * NFG + 4);
        const float xv[8] = {xlo.x, xlo.y, xlo.z, xlo.w, xhi.x, xhi.y, xhi.z, xhi.w};
        float xr[8];
#pragma unroll
        for (int o = 0; o < 8; ++o) {
            float s = beh[o];
#pragma unroll
            for (int f = 0; f < 8; ++f) s = fmaf(xv[f], Weh[f * 8 + o], s);
            xr[o] = fmaxf(s, 0.f);
        }
        xs4[r * 2]     = make_float4(xr[0], xr[1], xr[2], xr[3]);
        xs4[r * 2 + 1] = make_float4(xr[4], xr[5], xr[6], xr[7]);
    }
    __syncthreads();

    // ---- per-(n,g): a row, u, w ----
    {
        const int n = tid >> 2, g = tid & 3;
        const float4 xlo = xs4[n * 2], xhi = xs4[n * 2 + 1];
        const float xr[8] = {xlo.x, xlo.y, xlo.z, xlo.w, xhi.x, xhi.y, xhi.z, xhi.w};
        float av[8];
#pragma unroll
        for (int o = 0; o < 8; ++o) {
            float s = 0.f;
#pragma unroll
            for (int f = 0; f < 8; ++f) s = fmaf(xr[f], Msh[g * 64 + f * 8 + o], s);
            av[o] = s;
        }
        as4[(n * NG + g) * 2]     = make_float4(av[0], av[1], av[2], av[3]);
        as4[(n * NG + g) * 2 + 1] = make_float4(av[4], av[5], av[6], av[7]);
        float u = 0.f, w = 0.f;
#pragma unroll
        for (int f = 0; f < 8; ++f) {
            u = fmaf(xr[f], ush[g * 8 + f], u);
            w = fmaf(xr[f], vsh[g * 8 + f], w);
        }
        ((float*)&un4[n])[g] = u;
        ((float*)&wn4[n])[g] = w + csh[g];
    }
    __syncthreads();

    // ---- main: single pass over m (shifted-exp softmax, no max pass) ----
    const int n = tid >> 2, c = tid & 3;
    const float thr2 = (gtype[0] == 0) ? 100.0f : 16.0f;

    float a[NG][NFG];
#pragma unroll
    for (int g = 0; g < NG; ++g) {
        const float4 lo = as4[(n * NG + g) * 2], hi = as4[(n * NG + g) * 2 + 1];
        a[g][0] = lo.x; a[g][1] = lo.y; a[g][2] = lo.z; a[g][3] = lo.w;
        a[g][4] = hi.x; a[g][5] = hi.y; a[g][6] = hi.z; a[g][7] = hi.w;
    }
    const float4 u4 = un4[n];
    const float uu[NG] = {u4.x, u4.y, u4.z, u4.w};
    const float4 prw = pos4[n];
    const float pnx = prw.x, pny = prw.y, rn = prw.z;

    float sum[NG] = {0.f, 0.f, 0.f, 0.f};
    float agg[NG][NFG] = {};

#pragma unroll 4
    for (int i = 0; i < 32; ++i) {
        const int m = (i << 2) | c;
        const float4 xa = xs4[m * 2], xb = xs4[m * 2 + 1];
        const float4 pm = pos4[m];
        const float4 wm = wn4[m];
        const bool msk = asm_mask(pnx, pny, rn, pm.x, pm.y, pm.z, thr2);
        const float wmg[NG] = {wm.x, wm.y, wm.z, wm.w};
#pragma unroll
        for (int g = 0; g < NG; ++g) {
            float s = uu[g] + wmg[g];
            s = fmaf(a[g][0], xa.x, s); s = fmaf(a[g][1], xa.y, s);
            s = fmaf(a[g][2], xa.z, s); s = fmaf(a[g][3], xa.w, s);
            s = fmaf(a[g][4], xb.x, s); s = fmaf(a[g][5], xb.y, s);
            s = fmaf(a[g][6], xb.z, s); s = fmaf(a[g][7], xb.w, s);
            float e = __builtin_amdgcn_exp2f(fmaf(s, EXP_C, -EXP_SH));
            e = msk ? 0.f : e;
            sum[g] += e;
            agg[g][0] = fmaf(e, xa.x, agg[g][0]); agg[g][1] = fmaf(e, xa.y, agg[g][1]);
            agg[g][2] = fmaf(e, xa.z, agg[g][2]); agg[g][3] = fmaf(e, xa.w, agg[g][3]);
            agg[g][4] = fmaf(e, xb.x, agg[g][4]); agg[g][5] = fmaf(e, xb.y, agg[g][5]);
            agg[g][6] = fmaf(e, xb.z, agg[g][6]); agg[g][7] = fmaf(e, xb.w, agg[g][7]);
        }
    }

    // combine the 4 c-lanes (lanes 4k..4k+3 of the wave)
#pragma unroll
    for (int st = 1; st <= 2; st <<= 1) {
#pragma unroll
        for (int g = 0; g < NG; ++g) {
            sum[g] += __shfl_xor(sum[g], st);
#pragma unroll
            for (int f = 0; f < 8; ++f) agg[g][f] += __shfl_xor(agg[g][f], st);
        }
    }

    float inv[NG];
#pragma unroll
    for (int g = 0; g < NG; ++g) inv[g] = 1.0f / sum[g];
    if (c == 0) invws[b * Nn + n] = inv[NG - 1];

    // feats: this lane computes o = 2c, 2c+1
    float hv[2];
#pragma unroll
    for (int k = 0; k < 2; ++k) {
        const int o = c * 2 + k;
        float h = 0.f;
#pragma unroll
        for (int g = 0; g < NG; ++g) {
            float t = 0.f;
#pragma unroll
            for (int f = 0; f < 8; ++f) t = fmaf(agg[g][f], Wgsh[g * 64 + f * 8 + o], t);
            h += fmaxf(t * inv[g], 0.f);
        }
        hv[k] = h * 0.25f;
    }
    *(float2*)(out + ((size_t)b * Nn + n) * NFG + c * 2) = make_float2(hv[0], hv[1]);
}

// ---------------- kernel B: write attn of last head (coalesced) ----------------
// grid (512, 4), block 256: b = bx, row-quarter rq = by; thread: m = tid&127,
// rh = tid>>7 -> 16 rows each. Stores lane-contiguous in m.
__global__ __launch_bounds__(256) void kernelB(
    const float* __restrict__ X, const float* __restrict__ boxes,
    const float* __restrict__ We, const float* __restrict__ be,
    const int* __restrict__ gtype, const float* __restrict__ ws,
    const float* __restrict__ invws, float* __restrict__ out) {

    __shared__ float4 xs4[Nn * 2];
    __shared__ float Weh[64], beh[8];
    __shared__ float M3h[64], vs3h[8], us3h[8];
    __shared__ float4 a3s4[32 * 2];
    __shared__ float u3s[32], inv3s[32];
    __shared__ float4 prow[32];          // x, y, rr(asm), 0
    __shared__ float cs3h;

    const int b = blockIdx.x, rq = blockIdx.y;
    const int tid = threadIdx.x;
    const int m = tid & 127, rh = tid >> 7;

    if (tid < 64) Weh[tid] = We[tid];
    if (tid >= 64 && tid < 128) M3h[tid - 64] = ws[192 + (tid - 64)];
    if (tid >= 128 && tid < 136) vs3h[tid - 128] = ws[312 + (tid - 128)];
    if (tid >= 136 && tid < 144) us3h[tid - 136] = ws[280 + (tid - 136)];
    if (tid >= 144 && tid < 152) beh[tid - 144] = be[tid - 144];
    if (tid == 152) cs3h = ws[323];
    if (tid >= 160 && tid < 192) {
        const int j = tid - 160;
        inv3s[j] = invws[b * Nn + rq * 32 + j];
        const float4 bx = *(const float4*)(boxes + ((size_t)b * Nn + rq * 32 + j) * 4);
        prow[j] = make_float4(bx.x, bx.y, asm_rr(bx.x, bx.y), 0.f);
    }
    __syncthreads();

    if (tid < Nn) {
        const int r = tid;
        const float4 xlo = *(const float4*)(X + ((size_t)b * Nn + r) * NFG);
        const float4 xhi = *(const float4*)(X + ((size_t)b * Nn + r) * NFG + 4);
        const float xv[8] = {xlo.x, xlo.y, xlo.z, xlo.w, xhi.x, xhi.y, xhi.z, xhi.w};
        float xr[8];
#pragma unroll
        for (int o = 0; o < 8; ++o) {
            float s = beh[o];
#pragma unroll
            for (int f = 0; f < 8; ++f) s = fmaf(xv[f], Weh[f * 8 + o], s);
            xr[o] = fmaxf(s, 0.f);
        }
        xs4[r * 2]     = make_float4(xr[0], xr[1], xr[2], xr[3]);
        xs4[r * 2 + 1] = make_float4(xr[4], xr[5], xr[6], xr[7]);
    }
    __syncthreads();

    {   // a3 rows for this block's 32 rows (+ u3)
        const int r = tid >> 3, o = tid & 7;
        const int nr = rq * 32 + r;
        const float4 xlo = xs4[nr * 2], xhi = xs4[nr * 2 + 1];
        const float xr[8] = {xlo.x, xlo.y, xlo.z, xlo.w, xhi.x, xhi.y, xhi.z, xhi.w};
        float s = 0.f;
#pragma unroll
        for (int f = 0; f < 8; ++f) s = fmaf(xr[f], M3h[f * 8 + o], s);
        ((float*)&a3s4[r * 2])[o] = s;
        if (o == 0) {
            float u = 0.f;
#pragma unroll
            for (int f = 0; f < 8; ++f) u = fmaf(xr[f], us3h[f], u);
            u3s[r] = u;
        }
    }
    __syncthreads();

    // own column m data (mirrors kernel A's fp32 expression forms exactly)
    const float4 xlo = xs4[m * 2], xhi = xs4[m * 2 + 1];
    const float xm[8] = {xlo.x, xlo.y, xlo.z, xlo.w, xhi.x, xhi.y, xhi.z, xhi.w};
    float w3 = 0.f;
#pragma unroll
    for (int f = 0; f < 8; ++f) w3 = fmaf(xm[f], vs3h[f], w3);
    const float w3m = w3 + cs3h;
    const float4 bxm = *(const float4*)(boxes + ((size_t)b * Nn + m) * 4);
    const float pxm = bxm.x, pym = bxm.y;
    const float rrm = asm_rr(bxm.x, bxm.y);
    const float thr2 = (gtype[0] == 0) ? 100.0f : 16.0f;

#pragma unroll 4
    for (int j = 0; j < 16; ++j) {
        const int r = rh * 16 + j;
        const int nrow = rq * 32 + r;
        const float4 pr = prow[r];
        const bool msk = asm_mask(pr.x, pr.y, pr.z, pxm, pym, rrm, thr2);
        const float4 alo = a3s4[r * 2], ahi = a3s4[r * 2 + 1];
        float s = u3s[r] + w3m;
        s = fmaf(alo.x, xm[0], s); s = fmaf(alo.y, xm[1], s);
        s = fmaf(alo.z, xm[2], s); s = fmaf(alo.w, xm[3], s);
        s = fmaf(ahi.x, xm[4], s); s = fmaf(ahi.y, xm[5], s);
        s = fmaf(ahi.z, xm[6], s); s = fmaf(ahi.w, xm[7], s);
        float e = __builtin_amdgcn_exp2f(fmaf(s, EXP_C, -EXP_SH));
        e = msk ? 0.f : e;
        out[(size_t)FEATS + ((size_t)(b * Nn + nrow)) * Nn + m] = e * inv3s[r];
    }
}

extern "C" void kernel_launch(void* const* d_in, const int* in_sizes, int n_in,
                              void* d_out, int out_size, void* d_ws, size_t ws_size,
                              hipStream_t stream) {
    const float* X     = (const float*)d_in[0];
    const float* boxes = (const float*)d_in[1];
    const float* We    = (const float*)d_in[2];
    const float* be    = (const float*)d_in[3];
    const float* Wt    = (const float*)d_in[4];
    const float* bt    = (const float*)d_in[5];
    const float* Wp    = (const float*)d_in[6];
    const float* bp    = (const float*)d_in[7];
    const float* Wg    = (const float*)d_in[8];
    const int*   gt    = (const int*)d_in[9];
    float* out = (float*)d_out;
    float* ws  = (float*)d_ws;
    float* invws = ws + WS_INV;

    precompute_kernel<<<324, 64, 0, stream>>>(Wt, bt, Wp, bp, ws);
    kernelA<<<Bb, 512, 0, stream>>>(X, boxes, We, be, Wg, gt, ws, out, invws);
    kernelB<<<dim3(Bb, 4), 256, 0, stream>>>(X, boxes, We, be, gt, ws, invws, out);
}